// Round 3
// baseline (93.094 us; speedup 1.0000x reference)
//
#include <hip/hip_runtime.h>
#include <math.h>

#define N_FRAMES 4
#define N_FACES  320
#define N_VERTS  162
#define IMG_H    128
#define IMG_W    128
#define NWAVES   8
#define FPW      40            // faces per wave segment (320/8), one ballot round
#define REC_SZ   20            // floats per compacted face record

// LDS arena, phase A (prologue + main loop):
//   sv   @ 0    : 162*3 floats = 1944 B (pad 1952)
//   bb   @ 1952 : SoA [wave][4][48] = 6144 B
//   recs @ 8096 : [wave][FPW][REC_SZ] = 25600 B  -> total 33696 B
// phase B (after barrier, aliased over phase A):
//   red  @ 0     : 512*6 floats = 12288 B  (argmax + core-P partials)
//   hred @ 12288 : 8*96 floats  =  3072 B  (halo-ring P partials)
//   m20  @ 15360 : 160 floats   =   640 B  (20x8 mask tile for the 5x5 min-pool)
#define SV_OFF   0
#define BB_OFF   1952
#define BB_LD    48
#define REC_OFF  8096
#define ARENA_SZ 33696

// Record (REC_SZ floats): ax,ay,e0x,e0y, e1x,e1y,invden,origidx,
//                         z0,z1,z2,invL2_0, bx,by,e12x,e12y, cx,cy,invL2_1,invL2_2

// ---------- small math helpers (fp32, op-order matched to the JAX reference) ----------

__device__ __forceinline__ void q_to_aa(const float* q, float* aa) {
    float q1 = q[1], q2 = q[2], q3 = q[3];
    float sin_sq = (q1 * q1 + q2 * q2) + q3 * q3;
    float sin_t = sqrtf(sin_sq + 1e-20f);
    float cos_t = q[0];
    float two_theta = (cos_t < 0.0f) ? (2.0f * atan2f(-sin_t, -cos_t))
                                     : (2.0f * atan2f(sin_t, cos_t));
    float k = (sin_sq > 1e-12f) ? (two_theta / sin_t) : 2.0f;
    aa[0] = q1 * k; aa[1] = q2 * k; aa[2] = q3 * k;
}

__device__ __forceinline__ void aa_to_R(const float* aa, float* R) {
    float th = sqrtf(((aa[0] * aa[0] + aa[1] * aa[1]) + aa[2] * aa[2]) + 1e-12f);
    float kx = aa[0] / th, ky = aa[1] / th, kz = aa[2] / th;
    float K[9] = { 0.0f, -kz,  ky,
                   kz,  0.0f, -kx,
                  -ky,   kx, 0.0f };
    float s = sinf(th), c = cosf(th);
    float KK[9];
    for (int i = 0; i < 3; ++i)
        for (int j = 0; j < 3; ++j)
            KK[i*3+j] = (K[i*3+0] * K[0*3+j] + K[i*3+1] * K[1*3+j]) + K[i*3+2] * K[2*3+j];
    float omc = 1.0f - c;
    for (int i = 0; i < 9; ++i) {
        float eye = (i == 0 || i == 4 || i == 8) ? 1.0f : 0.0f;
        R[i] = (eye + s * K[i]) + omc * KK[i];
    }
}

__device__ __forceinline__ void mat3mul(const float* A, const float* B, float* C) {
    for (int i = 0; i < 3; ++i)
        for (int j = 0; j < 3; ++j)
            C[i*3+j] = (A[i*3+0] * B[0*3+j] + A[i*3+1] * B[1*3+j]) + A[i*3+2] * B[2*3+j];
}

// halo-ring pixel index h in [0,96) -> (row r in [0,8), col c in [0,20)) of the
// 20x8 (tile + 2px halo) region; the 16x4 core is r in [2,6), c in [2,18).
// Order: top 2 rows (40), bottom 2 rows (40), 4 middle rows x {0,1,18,19} (16).
__device__ __forceinline__ void halo_rc(int h, int* r, int* c) {
    if (h < 40)      { *r = h / 20;                *c = h % 20; }
    else if (h < 80) { int idx = h - 40; *r = 6 + idx / 20; *c = idx % 20; }
    else             { int s = h - 80; *r = 2 + (s >> 2);
                       int co = s & 3; *c = (co < 2) ? co : (16 + co); }
}

// (1 - prob) factor of one face at one pixel — op order identical to the core path.
__device__ __forceinline__ float face_mask_factor(
    float px, float py,
    float ax, float ay, float e0x, float e0y, float e1x, float e1y,
    float invden, float invL2_0,
    float bx, float by, float e12x, float e12y,
    float cx, float cy, float invL2_1, float invL2_2)
{
    float dx = px - ax, dy = py - ay;
    float w1 = (dx * e1y - dy * e1x) * invden;
    float w2 = (e0x * dy - e0y * dx) * invden;
    float w0 = (1.0f - w1) - w2;
    bool inside = (w0 >= 0.0f) & (w1 >= 0.0f) & (w2 >= 0.0f);
    // edge 0: a->b
    float t0 = fminf(fmaxf((dx * e0x + dy * e0y) * invL2_0, 0.0f), 1.0f);
    float x0 = dx - t0 * e0x, y0 = dy - t0 * e0y;
    float dd = x0 * x0 + y0 * y0;
    // edge 1: b->c
    float rx1 = px - bx, ry1 = py - by;
    float t1 = fminf(fmaxf((rx1 * e12x + ry1 * e12y) * invL2_1, 0.0f), 1.0f);
    float x1 = rx1 - t1 * e12x, y1 = ry1 - t1 * e12y;
    dd = fminf(dd, x1 * x1 + y1 * y1);
    // edge 2: c->a (edge vector = -e1, exact fp negation)
    float ex2 = -e1x, ey2 = -e1y;
    float rx2 = px - cx, ry2 = py - cy;
    float t2 = fminf(fmaxf((rx2 * ex2 + ry2 * ey2) * invL2_2, 0.0f), 1.0f);
    float x2 = rx2 - t2 * ex2, y2 = ry2 - t2 * ey2;
    dd = fminf(dd, x2 * x2 + y2 * y2);
    float d2 = inside ? 0.0f : dd;
    float prob = __expf(-7000.0f * d2);
    return 1.0f - prob;
}

// ---------- single fused kernel: setup + raster + texture + mask + 5x5 erode ----------
// Block = 512 threads = 8 waves, one 16x4 pixel tile (1 px/lane), one frame.
// BLOCK SWIZZLE: frame = blockIdx&3, tile = blockIdx>>2 (tile-major spreads the
// 4 heavy frames of one tile over 4 different XCDs/CUs).
// FACE BALANCING (new): setup wave w builds records for faces [40w,40w+40) and
// culls them vs the halo rect; the 8 cull bitmasks are published to LDS, then
// the block-wide relevant list (ascending face order, length R) is sliced into
// 8 equal contiguous chunks — wave w walks chunk w. This replaces "wave w
// processes only its own segment" (max_w F_w ~ 2x mean on clustered meshes).
// Bit-exactness: the cross-wave combine multiplies wave partials in wave order,
// and slices are contiguous ascending -> the global factor order is the SAME
// ascending face order as before (only partial-product grouping moves, ~1e-7
// on mask values). Argmax tie-break (ff < bf) is order-independent.
// Cull margin 0.0026 > 25*ln2/7000: culled faces contribute a factor that
// rounds to exactly 1.0f at every halo-region pixel and cannot be inside any
// core pixel. Dead-path gate: once ALL lanes have P==PA==PB==0 exactly, every
// further multiply is 0*finite==0 -> mask half provably dead, skipped.

__global__ void __launch_bounds__(512)
render_kernel(const float* __restrict__ verts_in,   // 162*3
              const float* __restrict__ transl,     // 6 floats
              const float* __restrict__ quat,       // 8 floats
              const float* __restrict__ expv,       // 1 float
              const int*   __restrict__ faces,      // 320*3
              const float* __restrict__ ffeat,      // (320,3,2)
              const float* __restrict__ tex,        // (3,256,256)
              float* __restrict__ out)              // (4,4,128,128)
{
    __shared__ __align__(16) char arena[ARENA_SZ];
    __shared__ float rotS[9];
    __shared__ unsigned long long wmaskS[NWAVES];   // per-wave cull bitmasks
    float* sv    = (float*)(arena + SV_OFF);
    float* bb    = (float*)(arena + BB_OFF);
    float* recs  = (float*)(arena + REC_OFF);
    float* red   = (float*)arena;                   // aliased; used after barrier
    float* hredp = (float*)(arena + 12288);
    float* m20   = (float*)(arena + 15360);

    int frame = blockIdx.x & 3;                     // tile-major, frame-minor
    int blk   = blockIdx.x >> 2;
    int tid   = threadIdx.x;
    int lane  = tid & 63;
    int wv    = __builtin_amdgcn_readfirstlane(tid >> 6);
    int tile_x = blk & 7, tile_y = blk >> 3;
    int j = tile_x * 16 + (lane & 15);
    int i = tile_y * 4 + (lane >> 4);

    float e = expv[0];

    // ---- prologue phase 1: rotation chain, thread 0 only -> LDS broadcast ----
    if (tid == 0) {
        float aa0[3], aa1[3], Rl[9], S[9];
        q_to_aa(quat, aa0);
        aa_to_R(aa0, Rl);
        q_to_aa(quat + 4, aa1);                     // angles (ROT_DIVIDE = 1)
        float arg[3];
        for (int t = 0; t < 3; ++t) arg[t] = (e * aa1[t]) / 4.0f;
        aa_to_R(arg, S);
        for (int t = 0; t < frame; ++t) {           // rot = rot @ rot_step, k times
            float nxt[9];
            mat3mul(Rl, S, nxt);
            for (int q = 0; q < 9; ++q) Rl[q] = nxt[q];
        }
        for (int q = 0; q < 9; ++q) rotS[q] = Rl[q];
    }
    __syncthreads();

    // ---- prologue phase 2: camera-space vertices for THIS frame ----
    if (tid < N_VERTS) {
        float te = (float)((double)frame / 3.0) * e;
        float vx = verts_in[tid*3+0], vy = verts_in[tid*3+1], vz = verts_in[tid*3+2];
        float dx_ = (rotS[0] * vx + rotS[1] * vy) + rotS[2] * vz;
        float dy_ = (rotS[3] * vx + rotS[4] * vy) + rotS[5] * vz;
        float dz_ = (rotS[6] * vx + rotS[7] * vy) + rotS[8] * vz;
        float x = (dx_ + transl[0]) + te * transl[3];
        float y = (dy_ + transl[1]) + te * transl[4];
        float z = (dz_ + transl[2]) + te * transl[5];
        z = z - 2.0f;                               // v_cam = verts - [0,0,CAM_DIST]
        sv[tid*3+0] = x; sv[tid*3+1] = y; sv[tid*3+2] = z;
    }
    __syncthreads();

    // ---- per-pixel coordinates & HALO rectangle (tile + 2 px each side) ----
    float px = (float)(-1.0 + 2.0 * (double)j / 127.0);
    float py = (float)( 1.0 - 2.0 * (double)i / 127.0);
    float txminH = (float)(-1.0 + 2.0 * (double)(tile_x * 16 - 2) / 127.0);
    float txmaxH = (float)(-1.0 + 2.0 * (double)(tile_x * 16 + 17) / 127.0);
    float tymaxH = (float)( 1.0 - 2.0 * (double)(tile_y * 4 - 2) / 127.0);
    float tyminH = (float)( 1.0 - 2.0 * (double)(tile_y * 4 + 5) / 127.0);

    // ---- prologue phase 3: per-wave face setup + ballot compaction + cull ----
    const float FOCAL = (float)(1.0 / tan(1.57 / 4.0));
    {
        bool valid = false;
        float ax=0, ay=0, bx=0, by=0, cx=0, cy=0, e0x=0, e0y=0, e1x=0, e1y=0;
        float e12x=0, e12y=0, z0=0, z1=0, z2=0, den=0;
        int f = wv * FPW + lane;
        if (lane < FPW) {
            int i0 = faces[f*3+0], i1 = faces[f*3+1], i2 = faces[f*3+2];
            const float* A = &sv[i0*3];
            const float* B = &sv[i1*3];
            const float* C = &sv[i2*3];
            float ux = B[0] - A[0], uy = B[1] - A[1];
            float wx = C[0] - A[0], wy = C[1] - A[1];
            float nz = ux * wy - uy * wx;           // sign of face-normal z
            float da = -A[2] + 1e-10f, db = -B[2] + 1e-10f, dc = -C[2] + 1e-10f;
            ax = (FOCAL * A[0]) / da; ay = (FOCAL * A[1]) / da;
            bx = (FOCAL * B[0]) / db; by = (FOCAL * B[1]) / db;
            cx = (FOCAL * C[0]) / dc; cy = (FOCAL * C[1]) / dc;
            e0x = bx - ax; e0y = by - ay;
            e1x = cx - ax; e1y = cy - ay;
            e12x = cx - bx; e12y = cy - by;
            den = e0x * e1y - e0y * e1x;
            z0 = A[2]; z1 = B[2]; z2 = C[2];
            valid = (fabsf(den) > 1e-10f) && (nz > 0.0f);
        }
        unsigned long long m = __ballot(valid);
        int cnt = __popcll(m);                      // wave-uniform
        if (valid) {
            unsigned long long lmask = (lane == 63) ? 0x7fffffffffffffffull
                                                    : ((1ull << lane) - 1ull);
            int pos = __popcll(m & lmask);
            float invden = 1.0f / den;
            float L2_0 = (e0x * e0x + e0y * e0y) + 1e-12f;
            float L2_1 = (e12x * e12x + e12y * e12y) + 1e-12f;
            float L2_2 = (e1x * e1x + e1y * e1y) + 1e-12f;   // |(-e1)|^2 == |e1|^2
            float4* r = (float4*)&recs[(wv * FPW + pos) * REC_SZ];
            r[0] = make_float4(ax, ay, e0x, e0y);
            r[1] = make_float4(e1x, e1y, invden, (float)f);
            r[2] = make_float4(z0, z1, z2, 1.0f / L2_0);
            r[3] = make_float4(bx, by, e12x, e12y);
            r[4] = make_float4(cx, cy, 1.0f / L2_1, 1.0f / L2_2);
            float* wbb = &bb[wv * 4 * BB_LD];
            wbb[0*BB_LD + pos] = fminf(fminf(ax, bx), cx);
            wbb[1*BB_LD + pos] = fminf(fminf(ay, by), cy);
            wbb[2*BB_LD + pos] = fmaxf(fmaxf(ax, bx), cx);
            wbb[3*BB_LD + pos] = fmaxf(fmaxf(ay, by), cy);
        }
        // cull: one vectorized bbox test per lane over THIS wave's compacted recs
        // (own-wave LDS write->read, compiler inserts lgkmcnt; no barrier needed)
        int l = (lane < FPW) ? lane : 0;
        const float* wbb = &bb[wv * 4 * BB_LD];
        float xmin = wbb[0*BB_LD + l], ymin = wbb[1*BB_LD + l];
        float xmax = wbb[2*BB_LD + l], ymax = wbb[3*BB_LD + l];
        float cdx = fmaxf(fmaxf(xmin - txmaxH, txminH - xmax), 0.0f);
        float cdy = fmaxf(fmaxf(ymin - tymaxH, tyminH - ymax), 0.0f);
        bool near = ((cdx * cdx + cdy * cdy) <= 0.0026f) && (lane < cnt);
        unsigned long long fm = __ballot(near);
        if (lane == 0) wmaskS[wv] = fm;
    }
    __syncthreads();          // all recs + all wmasks visible block-wide

    // ---- halo pixel coordinates for this lane (A: all lanes, B: lanes 0..31) ----
    float pxA, pyA, pxB = 0.0f, pyB = 0.0f;
    bool hasB = lane < 32;
    {
        int rA, cA; halo_rc(lane, &rA, &cA);
        int iA = tile_y * 4 + rA - 2, jA = tile_x * 16 + cA - 2;
        pxA = (float)(-1.0 + 2.0 * (double)jA / 127.0);
        pyA = (float)( 1.0 - 2.0 * (double)iA / 127.0);
        if (hasB) {
            int rB, cB; halo_rc(64 + lane, &rB, &cB);
            int iB = tile_y * 4 + rB - 2, jB = tile_x * 16 + cB - 2;
            pxB = (float)(-1.0 + 2.0 * (double)jB / 127.0);
            pyB = (float)( 1.0 - 2.0 * (double)iB / 127.0);
        }
    }

    // ---- slice the block-wide relevant-face list evenly across the 8 waves ----
    unsigned long long wm[NWAVES];
    int R = 0;
    #pragma unroll
    for (int w = 0; w < NWAVES; ++w) { wm[w] = wmaskS[w]; R += __popcll(wm[w]); }
    int q = R >> 3, rem = R & 7;
    int start = wv * q + min(wv, rem);
    int count = q + ((wv < rem) ? 1 : 0);

    // cursor to the start of this wave's slice (wave-uniform scalar walk)
    int seg = 0, csum = 0;
    unsigned long long cur = 0;
    if (count > 0) {
        for (;;) {
            int pc = __popcll(wm[seg]);
            if (csum + pc > start) break;
            csum += pc; ++seg;
        }
        cur = wm[seg];
        for (int k = csum; k < start; ++k) cur &= cur - 1;
    }

    // ---- single merged loop: core argmax + core P + halo PA/PB per face ----
    float best = -1e10f;
    int bestf = 0;
    float bw0 = 0.0f, bw1 = 0.0f, bw2 = 0.0f;
    float P = 1.0f;
    float PA = 1.0f, PB = hasB ? 1.0f : 0.0f;
    bool allzero = false;                          // wave-uniform: all P,PA,PB == 0

    for (int n = 0; n < count; ++n) {
        while (cur == 0ull) { ++seg; cur = wm[seg]; }
        int fc = __ffsll((unsigned long long)cur) - 1;     // wave-uniform
        cur &= cur - 1;
        const float* d = &recs[(seg * FPW + fc) * REC_SZ]; // uniform -> broadcast

        float ax = d[0], ay = d[1], e0x = d[2], e0y = d[3];
        float e1x = d[4], e1y = d[5], invden = d[6], fidx = d[7];
        float z0 = d[8], z1 = d[9], z2 = d[10];

        float dx = px - ax, dy = py - ay;
        float w1 = (dx * e1y - dy * e1x) * invden;
        float w2 = (e0x * dy - e0y * dx) * invden;
        float w0 = (1.0f - w1) - w2;
        bool inside = (w0 >= 0.0f) & (w1 >= 0.0f) & (w2 >= 0.0f);
        float zi = (w0 * z0 + w1 * z1) + w2 * z2;
        float score = inside ? zi : -1e10f;
        if (score > best) {
            best = score; bestf = (int)fidx; bw0 = w0; bw1 = w1; bw2 = w2;
        }

        if (!allzero) {                            // wave-uniform branch
            float invL2_0 = d[11];
            float bx = d[12], by = d[13], e12x = d[14], e12y = d[15];
            float cx = d[16], cy = d[17], invL2_1 = d[18], invL2_2 = d[19];
            // --- core pixel mask factor (op order identical to original) ---
            // edge 0: a->b
            float t0 = fminf(fmaxf((dx * e0x + dy * e0y) * invL2_0, 0.0f), 1.0f);
            float x0 = dx - t0 * e0x, y0 = dy - t0 * e0y;
            float dd = x0 * x0 + y0 * y0;
            // edge 1: b->c
            float rx1 = px - bx, ry1 = py - by;
            float t1 = fminf(fmaxf((rx1 * e12x + ry1 * e12y) * invL2_1, 0.0f), 1.0f);
            float x1 = rx1 - t1 * e12x, y1 = ry1 - t1 * e12y;
            dd = fminf(dd, x1 * x1 + y1 * y1);
            // edge 2: c->a (edge vector = -e1, exact fp negation)
            float ex2 = -e1x, ey2 = -e1y;
            float rx2 = px - cx, ry2 = py - cy;
            float t2 = fminf(fmaxf((rx2 * ex2 + ry2 * ey2) * invL2_2, 0.0f), 1.0f);
            float x2 = rx2 - t2 * ex2, y2 = ry2 - t2 * ey2;
            dd = fminf(dd, x2 * x2 + y2 * y2);

            float d2 = inside ? 0.0f : dd;
            float prob = __expf(-7000.0f * d2);
            P *= (1.0f - prob);

            // --- halo pixels (same factor op order; 0*finite==0 once dead) ---
            PA *= face_mask_factor(pxA, pyA, ax, ay, e0x, e0y, e1x, e1y,
                                   invden, invL2_0, bx, by, e12x, e12y,
                                   cx, cy, invL2_1, invL2_2);
            if (hasB)
                PB *= face_mask_factor(pxB, pyB, ax, ay, e0x, e0y, e1x, e1y,
                                       invden, invL2_0, bx, by, e12x, e12y,
                                       cx, cy, invL2_1, invL2_2);

            allzero = __all((P == 0.0f) & (PA == 0.0f) & (PB == 0.0f));
        }
    }

    // ---- cross-wave reduction (red/hred/m20 alias the arena: barrier both sides) ----
    __syncthreads();                               // all waves done with recs
    float* my = &red[tid * 6];
    my[0] = best; my[1] = __int_as_float(bestf);
    my[2] = bw0;  my[3] = bw1; my[4] = bw2; my[5] = P;
    hredp[wv * 96 + lane] = PA;
    if (hasB) hredp[wv * 96 + 64 + lane] = PB;
    __syncthreads();

    if (tid < 64) {
        float bbst = red[tid * 6 + 0];
        int   bf   = __float_as_int(red[tid * 6 + 1]);
        float r0 = red[tid * 6 + 2], r1 = red[tid * 6 + 3], r2 = red[tid * 6 + 4];
        float Pt = red[tid * 6 + 5];
        for (int w = 1; w < NWAVES; ++w) {
            const float* s = &red[(w * 64 + tid) * 6];
            float sc = s[0]; int ff = __float_as_int(s[1]);
            if ((sc > bbst) || ((sc == bbst) && (ff < bf))) {
                bbst = sc; bf = ff; r0 = s[2]; r1 = s[3]; r2 = s[4];
            }
            Pt *= s[5];
        }

        bool hit = bbst != -1e10f;
        float uv0 = 0.0f, uv1 = 0.0f;
        if (hit) {
            const float* fp = ffeat + bf * 6;
            uv0 = (fp[0] * r0 + fp[2] * r1) + fp[4] * r2;
            uv1 = (fp[1] * r0 + fp[3] * r1) + fp[5] * r2;
        }
        float u = fminf(fmaxf(uv0, 0.0f), 1.0f) * 255.0f;
        float v = (1.0f - fminf(fmaxf(uv1, 0.0f), 1.0f)) * 255.0f;
        float x0f = floorf(u), y0f = floorf(v);
        float fx = u - x0f, fy = v - y0f;
        int x0i = min(max((int)x0f, 0), 255);
        int x1i = min(x0i + 1, 255);
        int y0i = min(max((int)y0f, 0), 255);
        int y1i = min(y0i + 1, 255);

        for (int c = 0; c < 3; ++c) {
            const float* tc = tex + c * 65536;
            float t00 = tc[y0i * 256 + x0i];
            float t01 = tc[y0i * 256 + x1i];
            float t10 = tc[y1i * 256 + x0i];
            float t11 = tc[y1i * 256 + x1i];
            float val = (t00 * (1.0f - fx)) * (1.0f - fy);
            val = val + (t01 * fx) * (1.0f - fy);
            val = val + (t10 * (1.0f - fx)) * fy;
            val = val + (t11 * fx) * fy;
            out[((frame * 4 + c) * IMG_H + i) * IMG_W + j] = val;
        }
        // core mask value into the 20x8 tile (core pixels are always in-image)
        m20[(2 + (tid >> 4)) * 20 + (2 + (tid & 15))] = 1.0f - Pt;
    } else if (tid < 160) {
        // halo-ring mask: product over waves in ascending order (matches core)
        int h = tid - 64;
        float p = hredp[h];
        for (int w = 1; w < NWAVES; ++w) p *= hredp[w * 96 + h];
        int r, c; halo_rc(h, &r, &c);
        int ii = tile_y * 4 + r - 2, jj = tile_x * 16 + c - 2;
        bool inimg = (ii >= 0) && (ii < IMG_H) && (jj >= 0) && (jj < IMG_W);
        // out-of-image window cells are excluded from the min ('SAME' + -inf pad
        // in the reference max of -mask == +inf sentinel in the min of mask)
        m20[r * 20 + c] = inimg ? (1.0f - p) : 1e30f;
    }
    __syncthreads();

    // ---- fused 5x5 erode: min over the window from the LDS 20x8 mask tile ----
    if (tid < 64) {
        int r = 2 + (tid >> 4), c = 2 + (tid & 15);
        float mn = 1e30f;
        for (int dr = -2; dr <= 2; ++dr)
            for (int dc = -2; dc <= 2; ++dc)
                mn = fminf(mn, m20[(r + dr) * 20 + (c + dc)]);
        out[((frame * 4 + 3) * IMG_H + i) * IMG_W + j] = mn;
    }
}

// ---------- launcher: single dispatch, no workspace use ----------

extern "C" void kernel_launch(void* const* d_in, const int* in_sizes, int n_in,
                              void* d_out, int out_size, void* d_ws, size_t ws_size,
                              hipStream_t stream) {
    const float* vertices      = (const float*)d_in[0];
    const float* translation   = (const float*)d_in[1];
    const float* quaternion    = (const float*)d_in[2];
    const float* expv          = (const float*)d_in[3];
    const float* face_features = (const float*)d_in[4];
    const float* texture_maps  = (const float*)d_in[5];
    const int*   faces         = (const int*)d_in[6];
    float* out = (float*)d_out;
    (void)d_ws; (void)ws_size;

    render_kernel<<<N_FRAMES * 256, 512, 0, stream>>>(vertices, translation,
                                                      quaternion, expv, faces,
                                                      face_features, texture_maps,
                                                      out);
}

// Round 4
// 84.811 us; speedup vs baseline: 1.0977x; 1.0977x over previous
//
#include <hip/hip_runtime.h>
#include <math.h>

#define N_FRAMES 4
#define N_FACES  320
#define N_VERTS  162
#define IMG_H    128
#define IMG_W    128
#define NWAVES   8
#define FPW      40            // faces per wave (320/8), one ballot round
#define REC_SZ   20            // floats per compacted face record

// LDS arena, phase A (prologue + main loop):
//   sv   @ 0    : 162*3 floats = 1944 (pad 1952)
//   bb   @ 1952 : SoA [wave][4][48] = 6144
//   recs @ 8096 : [wave][FPW][REC_SZ] = 25600   -> total 33696
// phase B (after barrier, aliased over phase A):
//   red  @ 0    : 512*6 floats = 12288   (argmax + P partials)
#define SV_OFF   0
#define BB_OFF   1952
#define BB_LD    48
#define REC_OFF  8096
#define ARENA_SZ 33696

// Record (REC_SZ floats): ax,ay,e0x,e0y, e1x,e1y,invden,origidx,
//                         z0,z1,z2,invL2_0, bx,by,e12x,e12y, cx,cy,invL2_1,invL2_2

// ---------- small math helpers (fp32, op-order matched to the JAX reference) ----------

__device__ __forceinline__ void q_to_aa(const float* q, float* aa) {
    float q1 = q[1], q2 = q[2], q3 = q[3];
    float sin_sq = (q1 * q1 + q2 * q2) + q3 * q3;
    float sin_t = sqrtf(sin_sq + 1e-20f);
    float cos_t = q[0];
    float two_theta = (cos_t < 0.0f) ? (2.0f * atan2f(-sin_t, -cos_t))
                                     : (2.0f * atan2f(sin_t, cos_t));
    float k = (sin_sq > 1e-12f) ? (two_theta / sin_t) : 2.0f;
    aa[0] = q1 * k; aa[1] = q2 * k; aa[2] = q3 * k;
}

__device__ __forceinline__ void aa_to_R(const float* aa, float* R) {
    float th = sqrtf(((aa[0] * aa[0] + aa[1] * aa[1]) + aa[2] * aa[2]) + 1e-12f);
    float kx = aa[0] / th, ky = aa[1] / th, kz = aa[2] / th;
    float K[9] = { 0.0f, -kz,  ky,
                   kz,  0.0f, -kx,
                  -ky,   kx, 0.0f };
    float s = sinf(th), c = cosf(th);
    float KK[9];
    for (int i = 0; i < 3; ++i)
        for (int j = 0; j < 3; ++j)
            KK[i*3+j] = (K[i*3+0] * K[0*3+j] + K[i*3+1] * K[1*3+j]) + K[i*3+2] * K[2*3+j];
    float omc = 1.0f - c;
    for (int i = 0; i < 9; ++i) {
        float eye = (i == 0 || i == 4 || i == 8) ? 1.0f : 0.0f;
        R[i] = (eye + s * K[i]) + omc * KK[i];
    }
}

__device__ __forceinline__ void mat3mul(const float* A, const float* B, float* C) {
    for (int i = 0; i < 3; ++i)
        for (int j = 0; j < 3; ++j)
            C[i*3+j] = (A[i*3+0] * B[0*3+j] + A[i*3+1] * B[1*3+j]) + A[i*3+2] * B[2*3+j];
}

// ---------- fused kernel: per-block setup + rasterization + texture sample ----------
// Block = 512 threads = 8 waves, one 16x4 pixel tile (1 px/lane), one frame.
// BLOCK SWIZZLE (the one change vs the 87.9us version): frame = blockIdx&3,
// tile = blockIdx>>2. Tile-major order puts the 4 heavy frames of one screen
// tile on 4 DIFFERENT XCDs/CUs. The old frame-major mapping (frame=blockIdx>>8)
// placed blocks b, b+256, b+512, b+768 — the same hot tile in all 4 frames —
// on the SAME CU (256%8==0, one residency round at 4 blocks/CU), serializing
// the densest tile's work 4x on one CU (R1 rocprof: 42us, VALUBusy 27%,
// Occupancy 26%; de-clustering measured x0.45 on the fused variant R1->R2).
// Thread 0 computes the rotation chain once per block. Wave w owns faces
// [40w, 40w+40) (ballot-compacted). Cull vs the tile rect with margin
// 0.0026 > 25*ln2/7000 = 0.002476: skipped faces contribute a factor that
// rounds to exactly 1.0f at every tile pixel and cannot be inside -> bit-exact.
// P-dead-path skip: once ALL lanes have P == 0.0f exactly (pixel inside some
// face => factor exactly 0, and 0 * finite == 0 forever), the edge-distance/
// exp/product half of the body is provably dead and skipped -> bit-exact.

__global__ void __launch_bounds__(512)
render_kernel(const float* __restrict__ verts_in,   // 162*3
              const float* __restrict__ transl,     // 6 floats
              const float* __restrict__ quat,       // 8 floats
              const float* __restrict__ expv,       // 1 float
              const int*   __restrict__ faces,      // 320*3
              const float* __restrict__ ffeat,      // (320,3,2)
              const float* __restrict__ tex,        // (3,256,256)
              float* __restrict__ out,              // (4,4,128,128)
              float* __restrict__ maskbuf)          // (4,128,128)
{
    __shared__ __align__(16) char arena[ARENA_SZ];
    __shared__ float rotS[9];
    float* sv   = (float*)(arena + SV_OFF);
    float* bb   = (float*)(arena + BB_OFF);
    float* recs = (float*)(arena + REC_OFF);
    float* red  = (float*)arena;                    // aliased; used after barrier

    int frame = blockIdx.x & 3;                     // tile-major, frame-minor
    int blk   = blockIdx.x >> 2;
    int tid   = threadIdx.x;
    int lane  = tid & 63;
    int wv    = __builtin_amdgcn_readfirstlane(tid >> 6);
    int tile_x = blk & 7, tile_y = blk >> 3;
    int j = tile_x * 16 + (lane & 15);
    int i = tile_y * 4 + (lane >> 4);

    float e = expv[0];

    // ---- prologue phase 1: rotation chain, thread 0 only -> LDS broadcast ----
    if (tid == 0) {
        float aa0[3], aa1[3], Rl[9], S[9];
        q_to_aa(quat, aa0);
        aa_to_R(aa0, Rl);
        q_to_aa(quat + 4, aa1);                     // angles (ROT_DIVIDE = 1)
        float arg[3];
        for (int t = 0; t < 3; ++t) arg[t] = (e * aa1[t]) / 4.0f;
        aa_to_R(arg, S);
        for (int t = 0; t < frame; ++t) {           // rot = rot @ rot_step, k times
            float nxt[9];
            mat3mul(Rl, S, nxt);
            for (int q = 0; q < 9; ++q) Rl[q] = nxt[q];
        }
        for (int q = 0; q < 9; ++q) rotS[q] = Rl[q];
    }
    __syncthreads();

    // ---- prologue phase 2: camera-space vertices for THIS frame ----
    if (tid < N_VERTS) {
        float te = (float)((double)frame / 3.0) * e;
        float vx = verts_in[tid*3+0], vy = verts_in[tid*3+1], vz = verts_in[tid*3+2];
        float dx_ = (rotS[0] * vx + rotS[1] * vy) + rotS[2] * vz;
        float dy_ = (rotS[3] * vx + rotS[4] * vy) + rotS[5] * vz;
        float dz_ = (rotS[6] * vx + rotS[7] * vy) + rotS[8] * vz;
        float x = (dx_ + transl[0]) + te * transl[3];
        float y = (dy_ + transl[1]) + te * transl[4];
        float z = (dz_ + transl[2]) + te * transl[5];
        z = z - 2.0f;                               // v_cam = verts - [0,0,CAM_DIST]
        sv[tid*3+0] = x; sv[tid*3+1] = y; sv[tid*3+2] = z;
    }
    __syncthreads();

    // ---- prologue phase 3: per-wave face setup + ballot compaction ----
    const float FOCAL = (float)(1.0 / tan(1.57 / 4.0));
    int cnt;
    {
        bool valid = false;
        float ax=0, ay=0, bx=0, by=0, cx=0, cy=0, e0x=0, e0y=0, e1x=0, e1y=0;
        float e12x=0, e12y=0, z0=0, z1=0, z2=0, den=0;
        int f = wv * FPW + lane;
        if (lane < FPW) {
            int i0 = faces[f*3+0], i1 = faces[f*3+1], i2 = faces[f*3+2];
            const float* A = &sv[i0*3];
            const float* B = &sv[i1*3];
            const float* C = &sv[i2*3];
            float ux = B[0] - A[0], uy = B[1] - A[1];
            float wx = C[0] - A[0], wy = C[1] - A[1];
            float nz = ux * wy - uy * wx;           // sign of face-normal z
            float da = -A[2] + 1e-10f, db = -B[2] + 1e-10f, dc = -C[2] + 1e-10f;
            ax = (FOCAL * A[0]) / da; ay = (FOCAL * A[1]) / da;
            bx = (FOCAL * B[0]) / db; by = (FOCAL * B[1]) / db;
            cx = (FOCAL * C[0]) / dc; cy = (FOCAL * C[1]) / dc;
            e0x = bx - ax; e0y = by - ay;
            e1x = cx - ax; e1y = cy - ay;
            e12x = cx - bx; e12y = cy - by;
            den = e0x * e1y - e0y * e1x;
            z0 = A[2]; z1 = B[2]; z2 = C[2];
            valid = (fabsf(den) > 1e-10f) && (nz > 0.0f);
        }
        unsigned long long m = __ballot(valid);
        cnt = __popcll(m);                          // wave-uniform
        if (valid) {
            unsigned long long lmask = (lane == 63) ? 0x7fffffffffffffffull
                                                    : ((1ull << lane) - 1ull);
            int pos = __popcll(m & lmask);
            float invden = 1.0f / den;
            float L2_0 = (e0x * e0x + e0y * e0y) + 1e-12f;
            float L2_1 = (e12x * e12x + e12y * e12y) + 1e-12f;
            float L2_2 = (e1x * e1x + e1y * e1y) + 1e-12f;   // |(-e1)|^2 == |e1|^2
            float4* r = (float4*)&recs[(wv * FPW + pos) * REC_SZ];
            r[0] = make_float4(ax, ay, e0x, e0y);
            r[1] = make_float4(e1x, e1y, invden, (float)f);
            r[2] = make_float4(z0, z1, z2, 1.0f / L2_0);
            r[3] = make_float4(bx, by, e12x, e12y);
            r[4] = make_float4(cx, cy, 1.0f / L2_1, 1.0f / L2_2);
            float* wbb = &bb[wv * 4 * BB_LD];
            wbb[0*BB_LD + pos] = fminf(fminf(ax, bx), cx);
            wbb[1*BB_LD + pos] = fminf(fminf(ay, by), cy);
            wbb[2*BB_LD + pos] = fmaxf(fmaxf(ax, bx), cx);
            wbb[3*BB_LD + pos] = fmaxf(fmaxf(ay, by), cy);
        }
    }
    // No barrier needed: each wave reads only its own compacted segment.

    // ---- per-pixel coordinates & wave tile rectangle ----
    float px = (float)(-1.0 + 2.0 * (double)j / 127.0);
    float py = (float)( 1.0 - 2.0 * (double)i / 127.0);
    float txmin = (float)(-1.0 + 2.0 * (double)(tile_x * 16) / 127.0);
    float txmax = (float)(-1.0 + 2.0 * (double)(tile_x * 16 + 15) / 127.0);
    float tymax = (float)( 1.0 - 2.0 * (double)(tile_y * 4) / 127.0);
    float tymin = (float)( 1.0 - 2.0 * (double)(tile_y * 4 + 3) / 127.0);

    // ---- cull pass: one vectorized bbox test per lane -> relevance bitmask ----
    unsigned long long fmask;
    {
        int l = (lane < FPW) ? lane : 0;
        const float* wbb = &bb[wv * 4 * BB_LD];
        float xmin = wbb[0*BB_LD + l], ymin = wbb[1*BB_LD + l];
        float xmax = wbb[2*BB_LD + l], ymax = wbb[3*BB_LD + l];
        float cdx = fmaxf(fmaxf(xmin - txmax, txmin - xmax), 0.0f);
        float cdy = fmaxf(fmaxf(ymin - tymax, tymin - ymax), 0.0f);
        bool near = ((cdx * cdx + cdy * cdy) <= 0.0026f) && (lane < cnt);
        fmask = __ballot(near);
    }

    // ---- main loop: only relevant faces; P-dead-path skip once all lanes P==0 ----
    float best = -1e10f;
    int bestf = 0;
    float bw0 = 0.0f, bw1 = 0.0f, bw2 = 0.0f;
    float P = 1.0f;
    bool pzero = false;                            // wave-uniform: all lanes P==0

    while (fmask) {
        int fc = __ffsll((unsigned long long)fmask) - 1;   // wave-uniform
        fmask &= fmask - 1;
        const float* d = &recs[(wv * FPW + fc) * REC_SZ];  // uniform -> broadcast

        float ax = d[0], ay = d[1], e0x = d[2], e0y = d[3];
        float e1x = d[4], e1y = d[5], invden = d[6], fidx = d[7];
        float z0 = d[8], z1 = d[9], z2 = d[10];

        float dx = px - ax, dy = py - ay;
        float w1 = (dx * e1y - dy * e1x) * invden;
        float w2 = (e0x * dy - e0y * dx) * invden;
        float w0 = (1.0f - w1) - w2;
        bool inside = (w0 >= 0.0f) & (w1 >= 0.0f) & (w2 >= 0.0f);
        float zi = (w0 * z0 + w1 * z1) + w2 * z2;
        float score = inside ? zi : -1e10f;
        if (score > best) {
            best = score; bestf = (int)fidx; bw0 = w0; bw1 = w1; bw2 = w2;
        }

        if (!pzero) {                              // wave-uniform branch
            float invL2_0 = d[11];
            float bx = d[12], by = d[13], e12x = d[14], e12y = d[15];
            float cx = d[16], cy = d[17], invL2_1 = d[18], invL2_2 = d[19];
            // edge 0: a->b
            float t0 = fminf(fmaxf((dx * e0x + dy * e0y) * invL2_0, 0.0f), 1.0f);
            float x0 = dx - t0 * e0x, y0 = dy - t0 * e0y;
            float dd = x0 * x0 + y0 * y0;
            // edge 1: b->c
            float rx1 = px - bx, ry1 = py - by;
            float t1 = fminf(fmaxf((rx1 * e12x + ry1 * e12y) * invL2_1, 0.0f), 1.0f);
            float x1 = rx1 - t1 * e12x, y1 = ry1 - t1 * e12y;
            dd = fminf(dd, x1 * x1 + y1 * y1);
            // edge 2: c->a (edge vector = -e1, exact fp negation)
            float ex2 = -e1x, ey2 = -e1y;
            float rx2 = px - cx, ry2 = py - cy;
            float t2 = fminf(fmaxf((rx2 * ex2 + ry2 * ey2) * invL2_2, 0.0f), 1.0f);
            float x2 = rx2 - t2 * ex2, y2 = ry2 - t2 * ey2;
            dd = fminf(dd, x2 * x2 + y2 * y2);

            float d2 = inside ? 0.0f : dd;
            float prob = __expf(-7000.0f * d2);
            P *= (1.0f - prob);
            pzero = __all(P == 0.0f);
        }
    }

    // ---- cross-wave reduction (red aliases the arena: barrier both sides) ----
    __syncthreads();                               // all waves done with recs/bb
    float* my = &red[tid * 6];
    my[0] = best; my[1] = __int_as_float(bestf);
    my[2] = bw0;  my[3] = bw1; my[4] = bw2; my[5] = P;
    __syncthreads();

    if (tid < 64) {
        float bbst = red[tid * 6 + 0];
        int   bf   = __float_as_int(red[tid * 6 + 1]);
        float r0 = red[tid * 6 + 2], r1 = red[tid * 6 + 3], r2 = red[tid * 6 + 4];
        float Pt = red[tid * 6 + 5];
        for (int w = 1; w < NWAVES; ++w) {
            const float* s = &red[(w * 64 + tid) * 6];
            float sc = s[0]; int ff = __float_as_int(s[1]);
            if ((sc > bbst) || ((sc == bbst) && (ff < bf))) {
                bbst = sc; bf = ff; r0 = s[2]; r1 = s[3]; r2 = s[4];
            }
            Pt *= s[5];
        }

        bool hit = bbst != -1e10f;
        float uv0 = 0.0f, uv1 = 0.0f;
        if (hit) {
            const float* fp = ffeat + bf * 6;
            uv0 = (fp[0] * r0 + fp[2] * r1) + fp[4] * r2;
            uv1 = (fp[1] * r0 + fp[3] * r1) + fp[5] * r2;
        }
        float u = fminf(fmaxf(uv0, 0.0f), 1.0f) * 255.0f;
        float v = (1.0f - fminf(fmaxf(uv1, 0.0f), 1.0f)) * 255.0f;
        float x0f = floorf(u), y0f = floorf(v);
        float fx = u - x0f, fy = v - y0f;
        int x0i = min(max((int)x0f, 0), 255);
        int x1i = min(x0i + 1, 255);
        int y0i = min(max((int)y0f, 0), 255);
        int y1i = min(y0i + 1, 255);

        for (int c = 0; c < 3; ++c) {
            const float* tc = tex + c * 65536;
            float t00 = tc[y0i * 256 + x0i];
            float t01 = tc[y0i * 256 + x1i];
            float t10 = tc[y1i * 256 + x0i];
            float t11 = tc[y1i * 256 + x1i];
            float val = (t00 * (1.0f - fx)) * (1.0f - fy);
            val = val + (t01 * fx) * (1.0f - fy);
            val = val + (t10 * (1.0f - fx)) * fy;
            val = val + (t11 * fx) * fy;
            out[((frame * 4 + c) * IMG_H + i) * IMG_W + j] = val;
        }
        maskbuf[(frame * IMG_H + i) * IMG_W + j] = 1.0f - Pt;
    }
}

// ---------- kernel 2: 5x5 erode (window min over valid region) ----------

__global__ void __launch_bounds__(256)
erode_kernel(const float* __restrict__ maskbuf, float* __restrict__ out)
{
    int frame = blockIdx.x & 3;                    // tile-major here too
    int pix = (blockIdx.x >> 2) * 256 + threadIdx.x;
    int i = pix >> 7, j = pix & 127;
    float m = 1e30f;
    for (int di = -2; di <= 2; ++di) {
        int ii = i + di;
        if (ii < 0 || ii >= IMG_H) continue;
        for (int dj = -2; dj <= 2; ++dj) {
            int jj = j + dj;
            if (jj < 0 || jj >= IMG_W) continue;
            m = fminf(m, maskbuf[(frame * IMG_H + ii) * IMG_W + jj]);
        }
    }
    out[((frame * 4 + 3) * IMG_H + i) * IMG_W + j] = m;
}

// ---------- launcher ----------

extern "C" void kernel_launch(void* const* d_in, const int* in_sizes, int n_in,
                              void* d_out, int out_size, void* d_ws, size_t ws_size,
                              hipStream_t stream) {
    const float* vertices      = (const float*)d_in[0];
    const float* translation   = (const float*)d_in[1];
    const float* quaternion    = (const float*)d_in[2];
    const float* expv          = (const float*)d_in[3];
    const float* face_features = (const float*)d_in[4];
    const float* texture_maps  = (const float*)d_in[5];
    const int*   faces         = (const int*)d_in[6];
    float* out = (float*)d_out;

    float* maskbuf = (float*)d_ws;                 // 4*128*128 floats

    render_kernel<<<N_FRAMES * 256, 512, 0, stream>>>(vertices, translation,
                                                      quaternion, expv, faces,
                                                      face_features, texture_maps,
                                                      out, maskbuf);
    erode_kernel<<<N_FRAMES * 64, 256, 0, stream>>>(maskbuf, out);
}

// Round 5
// 82.456 us; speedup vs baseline: 1.1290x; 1.0286x over previous
//
#include <hip/hip_runtime.h>
#include <math.h>

#define N_FRAMES 4
#define N_FACES  320
#define N_VERTS  162
#define IMG_H    128
#define IMG_W    128
#define NWAVES   8
#define FPW      40            // faces per wave segment (320/8), one ballot round
#define REC_SZ   20            // floats per compacted face record

// LDS arena, phase A (prologue + main loop):
//   sv   @ 0    : 162*3 floats = 1944 B (pad 1952)
//   recs @ 1952 : block-wide compacted [<=320][REC_SZ] = 25600 B -> total 27552
// phase B (after barrier, aliased over phase A):
//   red  @ 0    : 512*6 floats = 12288 B  (argmax + P partials)
#define SV_OFF   0
#define REC_OFF  1952
#define ARENA_SZ 27552

// Record (REC_SZ floats): ax,ay,e0x,e0y, e1x,e1y,invden,origidx,
//                         z0,z1,z2,invL2_0, bx,by,e12x,e12y, cx,cy,invL2_1,invL2_2

// ---------- small math helpers (fp32, op-order matched to the JAX reference) ----------

__device__ __forceinline__ void q_to_aa(const float* q, float* aa) {
    float q1 = q[1], q2 = q[2], q3 = q[3];
    float sin_sq = (q1 * q1 + q2 * q2) + q3 * q3;
    float sin_t = sqrtf(sin_sq + 1e-20f);
    float cos_t = q[0];
    float two_theta = (cos_t < 0.0f) ? (2.0f * atan2f(-sin_t, -cos_t))
                                     : (2.0f * atan2f(sin_t, cos_t));
    float k = (sin_sq > 1e-12f) ? (two_theta / sin_t) : 2.0f;
    aa[0] = q1 * k; aa[1] = q2 * k; aa[2] = q3 * k;
}

__device__ __forceinline__ void aa_to_R(const float* aa, float* R) {
    float th = sqrtf(((aa[0] * aa[0] + aa[1] * aa[1]) + aa[2] * aa[2]) + 1e-12f);
    float kx = aa[0] / th, ky = aa[1] / th, kz = aa[2] / th;
    float K[9] = { 0.0f, -kz,  ky,
                   kz,  0.0f, -kx,
                  -ky,   kx, 0.0f };
    float s = sinf(th), c = cosf(th);
    float KK[9];
    for (int i = 0; i < 3; ++i)
        for (int j = 0; j < 3; ++j)
            KK[i*3+j] = (K[i*3+0] * K[0*3+j] + K[i*3+1] * K[1*3+j]) + K[i*3+2] * K[2*3+j];
    float omc = 1.0f - c;
    for (int i = 0; i < 9; ++i) {
        float eye = (i == 0 || i == 4 || i == 8) ? 1.0f : 0.0f;
        R[i] = (eye + s * K[i]) + omc * KK[i];
    }
}

__device__ __forceinline__ void mat3mul(const float* A, const float* B, float* C) {
    for (int i = 0; i < 3; ++i)
        for (int j = 0; j < 3; ++j)
            C[i*3+j] = (A[i*3+0] * B[0*3+j] + A[i*3+1] * B[1*3+j]) + A[i*3+2] * B[2*3+j];
}

// ---------- fused kernel: per-block setup + rasterization + texture sample ----------
// Block = 512 threads = 8 waves, one 16x4 pixel tile (1 px/lane), one frame.
// BLOCK SWIZZLE: frame = blockIdx&3, tile = blockIdx>>2 — tile-major spreads
// the 4 heavy frames of one screen tile over 4 different XCDs/CUs (R1->R2: x0.45).
// FACE COMPACTION + BALANCE (new, fixes R3's scratch-array regression): phase 3
// computes each face's record AND its cull test (bbox vs tile rect, margin
// 0.0026 > 25*ln2/7000) entirely in registers; a per-wave ballot + 8-entry LDS
// count array + block prefix writes ONLY relevant records, densely, in
// ascending face order. Wave w then walks the contiguous slice [w*R/8 ...) of
// the block-wide list with a plain indexed for-loop: no 8xULL local array (R3's
// scratch), no cursor walk, uniform trip count ceil(R/8) across waves (was
// max_w F_w ~ 2x mean). Global P-factor order stays ascending — only the
// partial-product grouping moves (~1e-7 on mask, far under tolerance; R3
// passed with identical absmax). Argmax tie-break is order-independent.
// P-dead-path skip: once ALL lanes have P == 0.0f exactly, the mask half of
// the body is provably dead (0 * finite == 0) and skipped.

__global__ void __launch_bounds__(512)
render_kernel(const float* __restrict__ verts_in,   // 162*3
              const float* __restrict__ transl,     // 6 floats
              const float* __restrict__ quat,       // 8 floats
              const float* __restrict__ expv,       // 1 float
              const int*   __restrict__ faces,      // 320*3
              const float* __restrict__ ffeat,      // (320,3,2)
              const float* __restrict__ tex,        // (3,256,256)
              float* __restrict__ out,              // (4,4,128,128)
              float* __restrict__ maskbuf)          // (4,128,128)
{
    __shared__ __align__(16) char arena[ARENA_SZ];
    __shared__ float rotS[9];
    __shared__ int   cntS[NWAVES];                  // per-wave relevant-face counts
    float* sv   = (float*)(arena + SV_OFF);
    float* recs = (float*)(arena + REC_OFF);
    float* red  = (float*)arena;                    // aliased; used after barrier

    int frame = blockIdx.x & 3;                     // tile-major, frame-minor
    int blk   = blockIdx.x >> 2;
    int tid   = threadIdx.x;
    int lane  = tid & 63;
    int wv    = __builtin_amdgcn_readfirstlane(tid >> 6);
    int tile_x = blk & 7, tile_y = blk >> 3;
    int j = tile_x * 16 + (lane & 15);
    int i = tile_y * 4 + (lane >> 4);

    float e = expv[0];

    // ---- prologue phase 1: rotation chain, thread 0 only -> LDS broadcast ----
    if (tid == 0) {
        float aa0[3], aa1[3], Rl[9], S[9];
        q_to_aa(quat, aa0);
        aa_to_R(aa0, Rl);
        q_to_aa(quat + 4, aa1);                     // angles (ROT_DIVIDE = 1)
        float arg[3];
        for (int t = 0; t < 3; ++t) arg[t] = (e * aa1[t]) / 4.0f;
        aa_to_R(arg, S);
        for (int t = 0; t < frame; ++t) {           // rot = rot @ rot_step, k times
            float nxt[9];
            mat3mul(Rl, S, nxt);
            for (int q = 0; q < 9; ++q) Rl[q] = nxt[q];
        }
        for (int q = 0; q < 9; ++q) rotS[q] = Rl[q];
    }
    __syncthreads();

    // ---- prologue phase 2: camera-space vertices for THIS frame ----
    if (tid < N_VERTS) {
        float te = (float)((double)frame / 3.0) * e;
        float vx = verts_in[tid*3+0], vy = verts_in[tid*3+1], vz = verts_in[tid*3+2];
        float dx_ = (rotS[0] * vx + rotS[1] * vy) + rotS[2] * vz;
        float dy_ = (rotS[3] * vx + rotS[4] * vy) + rotS[5] * vz;
        float dz_ = (rotS[6] * vx + rotS[7] * vy) + rotS[8] * vz;
        float x = (dx_ + transl[0]) + te * transl[3];
        float y = (dy_ + transl[1]) + te * transl[4];
        float z = (dz_ + transl[2]) + te * transl[5];
        z = z - 2.0f;                               // v_cam = verts - [0,0,CAM_DIST]
        sv[tid*3+0] = x; sv[tid*3+1] = y; sv[tid*3+2] = z;
    }
    __syncthreads();

    // ---- per-pixel coordinates & tile rectangle (needed by the cull test) ----
    float px = (float)(-1.0 + 2.0 * (double)j / 127.0);
    float py = (float)( 1.0 - 2.0 * (double)i / 127.0);
    float txmin = (float)(-1.0 + 2.0 * (double)(tile_x * 16) / 127.0);
    float txmax = (float)(-1.0 + 2.0 * (double)(tile_x * 16 + 15) / 127.0);
    float tymax = (float)( 1.0 - 2.0 * (double)(tile_y * 4) / 127.0);
    float tymin = (float)( 1.0 - 2.0 * (double)(tile_y * 4 + 3) / 127.0);

    // ---- prologue phase 3: face setup + in-register cull + block compaction ----
    const float FOCAL = (float)(1.0 / tan(1.57 / 4.0));
    int R, start, count;
    {
        bool keep = false;
        float ax=0, ay=0, bx=0, by=0, cx=0, cy=0, e0x=0, e0y=0, e1x=0, e1y=0;
        float e12x=0, e12y=0, z0=0, z1=0, z2=0, den=0;
        int f = wv * FPW + lane;
        if (lane < FPW) {
            int i0 = faces[f*3+0], i1 = faces[f*3+1], i2 = faces[f*3+2];
            const float* A = &sv[i0*3];
            const float* B = &sv[i1*3];
            const float* C = &sv[i2*3];
            float ux = B[0] - A[0], uy = B[1] - A[1];
            float wx = C[0] - A[0], wy = C[1] - A[1];
            float nz = ux * wy - uy * wx;           // sign of face-normal z
            float da = -A[2] + 1e-10f, db = -B[2] + 1e-10f, dc = -C[2] + 1e-10f;
            ax = (FOCAL * A[0]) / da; ay = (FOCAL * A[1]) / da;
            bx = (FOCAL * B[0]) / db; by = (FOCAL * B[1]) / db;
            cx = (FOCAL * C[0]) / dc; cy = (FOCAL * C[1]) / dc;
            e0x = bx - ax; e0y = by - ay;
            e1x = cx - ax; e1y = cy - ay;
            e12x = cx - bx; e12y = cy - by;
            den = e0x * e1y - e0y * e1x;
            z0 = A[2]; z1 = B[2]; z2 = C[2];
            bool valid = (fabsf(den) > 1e-10f) && (nz > 0.0f);
            // cull vs the tile rect, in registers (no bb LDS round-trip)
            float xmin = fminf(fminf(ax, bx), cx);
            float ymin = fminf(fminf(ay, by), cy);
            float xmax = fmaxf(fmaxf(ax, bx), cx);
            float ymax = fmaxf(fmaxf(ay, by), cy);
            float cdx = fmaxf(fmaxf(xmin - txmax, txmin - xmax), 0.0f);
            float cdy = fmaxf(fmaxf(ymin - tymax, tymin - ymax), 0.0f);
            keep = valid && ((cdx * cdx + cdy * cdy) <= 0.0026f);
        }
        unsigned long long m = __ballot(keep);
        if (lane == 0) cntS[wv] = __popcll(m);
        __syncthreads();                            // all wave counts visible
        int pre = 0; R = 0;
        #pragma unroll
        for (int w = 0; w < NWAVES; ++w) {          // 8 LDS broadcast reads
            int c = cntS[w];
            R += c;
            if (w < wv) pre += c;                   // wave-uniform accumulate
        }
        if (keep) {
            unsigned long long lmask = (lane == 63) ? 0x7fffffffffffffffull
                                                    : ((1ull << lane) - 1ull);
            int pos = pre + __popcll(m & lmask);    // block-wide ascending order
            float invden = 1.0f / den;
            float L2_0 = (e0x * e0x + e0y * e0y) + 1e-12f;
            float L2_1 = (e12x * e12x + e12y * e12y) + 1e-12f;
            float L2_2 = (e1x * e1x + e1y * e1y) + 1e-12f;   // |(-e1)|^2 == |e1|^2
            float4* r = (float4*)&recs[pos * REC_SZ];
            r[0] = make_float4(ax, ay, e0x, e0y);
            r[1] = make_float4(e1x, e1y, invden, (float)f);
            r[2] = make_float4(z0, z1, z2, 1.0f / L2_0);
            r[3] = make_float4(bx, by, e12x, e12y);
            r[4] = make_float4(cx, cy, 1.0f / L2_1, 1.0f / L2_2);
        }
        __syncthreads();                            // compacted list visible
        int q = R >> 3, rem = R & 7;
        start = wv * q + min(wv, rem);
        count = q + ((wv < rem) ? 1 : 0);
    }

    // ---- main loop: balanced contiguous slice; P-dead-path skip once all P==0 ----
    float best = -1e10f;
    int bestf = 0;
    float bw0 = 0.0f, bw1 = 0.0f, bw2 = 0.0f;
    float P = 1.0f;
    bool pzero = false;                            // wave-uniform: all lanes P==0

    for (int n = 0; n < count; ++n) {
        const float* d = &recs[(start + n) * REC_SZ];      // uniform -> broadcast

        float ax = d[0], ay = d[1], e0x = d[2], e0y = d[3];
        float e1x = d[4], e1y = d[5], invden = d[6], fidx = d[7];
        float z0 = d[8], z1 = d[9], z2 = d[10];

        float dx = px - ax, dy = py - ay;
        float w1 = (dx * e1y - dy * e1x) * invden;
        float w2 = (e0x * dy - e0y * dx) * invden;
        float w0 = (1.0f - w1) - w2;
        bool inside = (w0 >= 0.0f) & (w1 >= 0.0f) & (w2 >= 0.0f);
        float zi = (w0 * z0 + w1 * z1) + w2 * z2;
        float score = inside ? zi : -1e10f;
        if (score > best) {
            best = score; bestf = (int)fidx; bw0 = w0; bw1 = w1; bw2 = w2;
        }

        if (!pzero) {                              // wave-uniform branch
            float invL2_0 = d[11];
            float bx = d[12], by = d[13], e12x = d[14], e12y = d[15];
            float cx = d[16], cy = d[17], invL2_1 = d[18], invL2_2 = d[19];
            // edge 0: a->b
            float t0 = fminf(fmaxf((dx * e0x + dy * e0y) * invL2_0, 0.0f), 1.0f);
            float x0 = dx - t0 * e0x, y0 = dy - t0 * e0y;
            float dd = x0 * x0 + y0 * y0;
            // edge 1: b->c
            float rx1 = px - bx, ry1 = py - by;
            float t1 = fminf(fmaxf((rx1 * e12x + ry1 * e12y) * invL2_1, 0.0f), 1.0f);
            float x1 = rx1 - t1 * e12x, y1 = ry1 - t1 * e12y;
            dd = fminf(dd, x1 * x1 + y1 * y1);
            // edge 2: c->a (edge vector = -e1, exact fp negation)
            float ex2 = -e1x, ey2 = -e1y;
            float rx2 = px - cx, ry2 = py - cy;
            float t2 = fminf(fmaxf((rx2 * ex2 + ry2 * ey2) * invL2_2, 0.0f), 1.0f);
            float x2 = rx2 - t2 * ex2, y2 = ry2 - t2 * ey2;
            dd = fminf(dd, x2 * x2 + y2 * y2);

            float d2 = inside ? 0.0f : dd;
            float prob = __expf(-7000.0f * d2);
            P *= (1.0f - prob);
            pzero = __all(P == 0.0f);
        }
    }

    // ---- cross-wave reduction (red aliases the arena: barrier both sides) ----
    __syncthreads();                               // all waves done with recs
    float* my = &red[tid * 6];
    my[0] = best; my[1] = __int_as_float(bestf);
    my[2] = bw0;  my[3] = bw1; my[4] = bw2; my[5] = P;
    __syncthreads();

    if (tid < 64) {
        float bbst = red[tid * 6 + 0];
        int   bf   = __float_as_int(red[tid * 6 + 1]);
        float r0 = red[tid * 6 + 2], r1 = red[tid * 6 + 3], r2 = red[tid * 6 + 4];
        float Pt = red[tid * 6 + 5];
        for (int w = 1; w < NWAVES; ++w) {
            const float* s = &red[(w * 64 + tid) * 6];
            float sc = s[0]; int ff = __float_as_int(s[1]);
            if ((sc > bbst) || ((sc == bbst) && (ff < bf))) {
                bbst = sc; bf = ff; r0 = s[2]; r1 = s[3]; r2 = s[4];
            }
            Pt *= s[5];                             // wave order = ascending slices
        }

        bool hit = bbst != -1e10f;
        float uv0 = 0.0f, uv1 = 0.0f;
        if (hit) {
            const float* fp = ffeat + bf * 6;
            uv0 = (fp[0] * r0 + fp[2] * r1) + fp[4] * r2;
            uv1 = (fp[1] * r0 + fp[3] * r1) + fp[5] * r2;
        }
        float u = fminf(fmaxf(uv0, 0.0f), 1.0f) * 255.0f;
        float v = (1.0f - fminf(fmaxf(uv1, 0.0f), 1.0f)) * 255.0f;
        float x0f = floorf(u), y0f = floorf(v);
        float fx = u - x0f, fy = v - y0f;
        int x0i = min(max((int)x0f, 0), 255);
        int x1i = min(x0i + 1, 255);
        int y0i = min(max((int)y0f, 0), 255);
        int y1i = min(y0i + 1, 255);

        for (int c = 0; c < 3; ++c) {
            const float* tc = tex + c * 65536;
            float t00 = tc[y0i * 256 + x0i];
            float t01 = tc[y0i * 256 + x1i];
            float t10 = tc[y1i * 256 + x0i];
            float t11 = tc[y1i * 256 + x1i];
            float val = (t00 * (1.0f - fx)) * (1.0f - fy);
            val = val + (t01 * fx) * (1.0f - fy);
            val = val + (t10 * (1.0f - fx)) * fy;
            val = val + (t11 * fx) * fy;
            out[((frame * 4 + c) * IMG_H + i) * IMG_W + j] = val;
        }
        maskbuf[(frame * IMG_H + i) * IMG_W + j] = 1.0f - Pt;
    }
}

// ---------- kernel 2: 5x5 erode (window min over valid region) ----------

__global__ void __launch_bounds__(256)
erode_kernel(const float* __restrict__ maskbuf, float* __restrict__ out)
{
    int frame = blockIdx.x & 3;                    // tile-major here too
    int pix = (blockIdx.x >> 2) * 256 + threadIdx.x;
    int i = pix >> 7, j = pix & 127;
    float m = 1e30f;
    for (int di = -2; di <= 2; ++di) {
        int ii = i + di;
        if (ii < 0 || ii >= IMG_H) continue;
        for (int dj = -2; dj <= 2; ++dj) {
            int jj = j + dj;
            if (jj < 0 || jj >= IMG_W) continue;
            m = fminf(m, maskbuf[(frame * IMG_H + ii) * IMG_W + jj]);
        }
    }
    out[((frame * 4 + 3) * IMG_H + i) * IMG_W + j] = m;
}

// ---------- launcher ----------

extern "C" void kernel_launch(void* const* d_in, const int* in_sizes, int n_in,
                              void* d_out, int out_size, void* d_ws, size_t ws_size,
                              hipStream_t stream) {
    const float* vertices      = (const float*)d_in[0];
    const float* translation   = (const float*)d_in[1];
    const float* quaternion    = (const float*)d_in[2];
    const float* expv          = (const float*)d_in[3];
    const float* face_features = (const float*)d_in[4];
    const float* texture_maps  = (const float*)d_in[5];
    const int*   faces         = (const int*)d_in[6];
    float* out = (float*)d_out;

    float* maskbuf = (float*)d_ws;                 // 4*128*128 floats

    render_kernel<<<N_FRAMES * 256, 512, 0, stream>>>(vertices, translation,
                                                      quaternion, expv, faces,
                                                      face_features, texture_maps,
                                                      out, maskbuf);
    erode_kernel<<<N_FRAMES * 64, 256, 0, stream>>>(maskbuf, out);
}